// Round 4
// baseline (269.821 us; speedup 1.0000x reference)
//
#include <hip/hip_runtime.h>
#include <hip/hip_bf16.h>

typedef __attribute__((ext_vector_type(4))) float  f32x4;
typedef __attribute__((ext_vector_type(4))) int    i32x4;
typedef __attribute__((ext_vector_type(8))) short  s16x8;

static constexpr int Kd = 4096, Nd = 16384, Md = 1024;
static constexpr int BK = 64;
static constexpr int NT = Kd / BK;   // 64 K-tiles

// ---------- helpers ----------

__device__ __forceinline__ unsigned short f32_to_bf16_rne(float f) {
    unsigned u = __float_as_uint(f);
    unsigned r = u + 0x7FFFu + ((u >> 16) & 1u);
    return (unsigned short)(r >> 16);
}

__device__ __forceinline__ unsigned short i32_to_bf16_exact(int v) {
    return (unsigned short)(__float_as_uint((float)v) >> 16);
}

__device__ __forceinline__ void gload16(const unsigned short* g, unsigned short* l) {
    __builtin_amdgcn_global_load_lds(
        (const __attribute__((address_space(1))) void*)g,
        (__attribute__((address_space(3))) void*)l, 16, 0, 0);
}

// ---------- conversion kernels (near BW floor, unchanged) ----------

__global__ __launch_bounds__(256) void convert_w_kernel(
    const int* __restrict__ wq, unsigned short* __restrict__ wb) {
    const int ngroups = (Nd / 8) * Kd;
    int g = blockIdx.x * 256 + threadIdx.x;
    const int stride = gridDim.x * 256;
    for (; g < ngroups; g += stride) {
        const int* src = wq + (size_t)g * 8;
        i32x4 v0 = *(const i32x4*)(src);
        i32x4 v1 = *(const i32x4*)(src + 4);
        s16x8 o;
        o[0] = (short)i32_to_bf16_exact(v0[0]);
        o[1] = (short)i32_to_bf16_exact(v0[1]);
        o[2] = (short)i32_to_bf16_exact(v0[2]);
        o[3] = (short)i32_to_bf16_exact(v0[3]);
        o[4] = (short)i32_to_bf16_exact(v1[0]);
        o[5] = (short)i32_to_bf16_exact(v1[1]);
        o[6] = (short)i32_to_bf16_exact(v1[2]);
        o[7] = (short)i32_to_bf16_exact(v1[3]);
        *(s16x8*)(wb + (size_t)g * 8) = o;
    }
}

__global__ __launch_bounds__(256) void convert_x_kernel(
    const float* __restrict__ x, unsigned short* __restrict__ xb) {
    const int ngroups = (Md / 8) * Kd;
    int g = blockIdx.x * 256 + threadIdx.x;
    const int stride = gridDim.x * 256;
    for (; g < ngroups; g += stride) {
        const float* src = x + (size_t)g * 8;
        f32x4 v0 = *(const f32x4*)(src);
        f32x4 v1 = *(const f32x4*)(src + 4);
        s16x8 o;
        o[0] = (short)f32_to_bf16_rne(v0[0]);
        o[1] = (short)f32_to_bf16_rne(v0[1]);
        o[2] = (short)f32_to_bf16_rne(v0[2]);
        o[3] = (short)f32_to_bf16_rne(v0[3]);
        o[4] = (short)f32_to_bf16_rne(v1[0]);
        o[5] = (short)f32_to_bf16_rne(v1[1]);
        o[6] = (short)f32_to_bf16_rne(v1[2]);
        o[7] = (short)f32_to_bf16_rne(v1[3]);
        *(s16x8*)(xb + (size_t)g * 8) = o;
    }
}

// ---------- 256x256 GEMM, 2 barriers/tile, counted lgkmcnt ----------
// C[m,n] = scale[n] * sum_k A[m,k]*B[n,k] + bias[n]
// 8 waves = 2M x 4N; per-wave 128x64 out; BK=64; LDS 128 KiB, 2 slots.
// Per K-tile: issue ALL 24 ds_read_b128 up-front in pinned groups
// [A0+B0(12)][B1(4)][A1(8)], then counted lgkmcnt waits let later groups
// stream in UNDER the earlier quadrants' MFMAs:
//   lgkmcnt(12) -> Q(0,0); lgkmcnt(8) -> Q(0,1); lgkmcnt(0) -> Q(1,0);
//   B1 barrier; same-slot stages (t+2 lo); Q(1,1) (pure-register);
//   vmcnt(4); B2 barrier.
// Stage schedule: W1 (pre-B1): A_hi(t+1), B_hi(t+1) -> other slot (their
// regions' reads drained before t-1's B1, issued after t-1's B2).
// W2 (post-B1): A_lo(t+2), B_lo(t+2) -> same slot (reads drained via
// lgkmcnt(0) before B1). vmcnt(4) at tile end: oldest 8 VMEM ops = all of
// tile t+1's regions complete; the 4 in flight are tile t+2's lo stages.
// LDS XOR-swizzle: col_byte ^= (row&7)<<4; inverse folded into gload source.

#define BARRIER() asm volatile("s_barrier" ::: "memory")

#define SBAR() __builtin_amdgcn_sched_barrier(0)

#define LGKM(n) do {                                                           \
    asm volatile("s_waitcnt lgkmcnt(" #n ")" ::: "memory");                    \
    __builtin_amdgcn_sched_barrier(0);                                         \
} while (0)

#define STAGE_A(slot, h, kt) do {                                              \
    unsigned short* lb_ = &LDS[slot][0][h][w * 8][0];                          \
    gload16(Ab + (aRow0 + (h) * 64) * (size_t)Kd + (kt) * BK + gcol, lb_);     \
    gload16(Ab + (aRow0 + (h) * 64 + 128) * (size_t)Kd + (kt) * BK + gcol,     \
            lb_ + 64 * 64);                                                    \
} while (0)

#define STAGE_B(slot, j, kt) do {                                              \
    unsigned short* lb_ = &LDS[slot][1][j][w * 8][0];                          \
    gload16(Bw + (bRow0 + (j) * 32) * (size_t)Kd + (kt) * BK + gcol, lb_);     \
    gload16(Bw + (bRow0 + (j) * 32 + 128) * (size_t)Kd + (kt) * BK + gcol,     \
            lb_ + 64 * 64);                                                    \
} while (0)

#define READ_A(dst, slot, h) do {                                              \
    const char* lA_ = (const char*)&LDS[slot][0][h][0][0];                     \
    _Pragma("unroll")                                                          \
    for (int mi = 0; mi < 4; ++mi)                                             \
        _Pragma("unroll")                                                      \
        for (int kk = 0; kk < 2; ++kk) {                                       \
            const int row_ = wm * 64 + mi * 16 + lr;                           \
            const int col_ = (l4 * 16 + kk * 64) ^ xorv;                       \
            dst[mi][kk] = *(const s16x8*)(lA_ + row_ * 128 + col_);            \
        }                                                                      \
} while (0)

#define READ_B(dst, slot, j) do {                                              \
    const char* lB_ = (const char*)&LDS[slot][1][j][0][0];                     \
    _Pragma("unroll")                                                          \
    for (int ni = 0; ni < 2; ++ni)                                             \
        _Pragma("unroll")                                                      \
        for (int kk = 0; kk < 2; ++kk) {                                       \
            const int row_ = wn * 32 + ni * 16 + lr;                           \
            const int col_ = (l4 * 16 + kk * 64) ^ xorv;                       \
            dst[ni][kk] = *(const s16x8*)(lB_ + row_ * 128 + col_);            \
        }                                                                      \
} while (0)

#define MFMA_QUAD(h, j, AF, BF) do {                                           \
    __builtin_amdgcn_s_setprio(1);                                             \
    _Pragma("unroll")                                                          \
    for (int mi = 0; mi < 4; ++mi)                                             \
        _Pragma("unroll")                                                      \
        for (int ni = 0; ni < 2; ++ni)                                         \
            _Pragma("unroll")                                                  \
            for (int kk = 0; kk < 2; ++kk)                                     \
                acc[(h) * 4 + mi][(j) * 2 + ni] =                              \
                    __builtin_amdgcn_mfma_f32_16x16x32_bf16(                   \
                        AF[mi][kk], BF[ni][kk],                                \
                        acc[(h) * 4 + mi][(j) * 2 + ni], 0, 0, 0);             \
    __builtin_amdgcn_s_setprio(0);                                             \
} while (0)

#define VMCNT_TILE(t)                                                          \
    do {                                                                       \
        if ((t) + 2 < NT) asm volatile("s_waitcnt vmcnt(4)" ::: "memory");     \
        else              asm volatile("s_waitcnt vmcnt(0)" ::: "memory");     \
    } while (0)

#define TILE(slot, oslot, t) do {                                              \
    s16x8 afA[4][2], afB[4][2], bfA[2][2], bfB[2][2];                          \
    /* pinned read groups: [A0+B0]=12, [B1]=4, [A1]=8 */                       \
    READ_A(afA, slot, 0);                                                      \
    READ_B(bfA, slot, 0);                                                      \
    SBAR();                                                                    \
    READ_B(bfB, slot, 1);                                                      \
    SBAR();                                                                    \
    READ_A(afB, slot, 1);                                                      \
    SBAR();                                                                    \
    /* W1 stages -> other slot hi regions */                                   \
    if ((t) + 1 < NT) { STAGE_A(oslot, 1, (t) + 1);                            \
                        STAGE_B(oslot, 1, (t) + 1); }                          \
    LGKM(12);                                                                  \
    MFMA_QUAD(0, 0, afA, bfA);                                                 \
    LGKM(8);                                                                   \
    MFMA_QUAD(0, 1, afA, bfB);                                                 \
    LGKM(0);                                                                   \
    MFMA_QUAD(1, 0, afB, bfA);                                                 \
    BARRIER();  /* B1: every wave fully lgkm-drained before this */            \
    /* W2 stages -> same slot lo regions (t+2) */                              \
    if ((t) + 2 < NT) { STAGE_A(slot, 0, (t) + 2);                             \
                        STAGE_B(slot, 0, (t) + 2); }                           \
    MFMA_QUAD(1, 1, afB, bfB);  /* pure-register */                            \
    VMCNT_TILE(t);                                                             \
    BARRIER();  /* B2: tile t+1 regions complete for all waves */              \
} while (0)

__global__ __launch_bounds__(512, 2) void gemm8_kernel(
    const unsigned short* __restrict__ Ab,
    const unsigned short* __restrict__ Bw,
    const float* __restrict__ scale,
    const float* __restrict__ bias,
    float* __restrict__ C) {

    __shared__ __align__(16) unsigned short LDS[2][2][2][128][64];  // 128 KiB

    const int tid = threadIdx.x;
    const int l   = tid & 63;
    const int w   = tid >> 6;          // wave 0..7
    const int wm  = w >> 2;            // 0..1
    const int wn  = w & 3;             // 0..3
    const int lr  = l & 15;
    const int l4  = l >> 4;            // 0..3
    const int xorv = (lr & 7) << 4;

    // bijective XCD swizzle (256 wg, 32/XCD), m-fastest work order
    const int orig = blockIdx.x;
    const int work = (orig & 7) * 32 + (orig >> 3);
    const int gm0 = (work & 3) * 256;
    const int gn0 = (work >> 2) * 256;

    // staging source geometry (inverse of read-side XOR swizzle)
    const int g_log = (l & 7) ^ ((l >> 3) & 7);
    const int gcol  = g_log * 8;
    const size_t aRow0 = (size_t)(gm0 + w * 8 + (l >> 3));
    const size_t bRow0 = (size_t)(gn0 + (w >> 2) * 64 + (w & 3) * 8 + (l >> 3));

    f32x4 acc[8][4];
    #pragma unroll
    for (int i = 0; i < 8; ++i)
        #pragma unroll
        for (int j = 0; j < 4; ++j) {
            f32x4 z = {0.f, 0.f, 0.f, 0.f};
            acc[i][j] = z;
        }

    // prologue: tile0 complete + tile1 lo-regions
    STAGE_A(0, 0, 0); STAGE_B(0, 0, 0);
    STAGE_A(0, 1, 0); STAGE_B(0, 1, 0);
    STAGE_A(1, 0, 1); STAGE_B(1, 0, 1);
    asm volatile("s_waitcnt vmcnt(4)" ::: "memory");
    BARRIER();

    #pragma unroll 1
    for (int tt = 0; tt < NT / 2; ++tt) {
        TILE(0, 1, 2 * tt);
        TILE(1, 0, 2 * tt + 1);
    }

    // epilogue: C = scale[n]*acc + bias[n]
    // C/D layout: col = lane&15 (n), row = (lane>>4)*4 + reg (m)
    #pragma unroll
    for (int bj = 0; bj < 4; ++bj) {
        const int gn = gn0 + wn * 64 + bj * 16 + lr;
        const float sc = scale[gn];
        const float bi = bias[gn];
        #pragma unroll
        for (int ai = 0; ai < 8; ++ai) {
            const int gm = gm0 + wm * 128 + ai * 16 + l4 * 4;
            #pragma unroll
            for (int r = 0; r < 4; ++r)
                C[(size_t)(gm + r) * Nd + gn] = sc * acc[ai][bj][r] + bi;
        }
    }
}

// ---------- fallback (ws too small): slow but correct ----------

__global__ __launch_bounds__(256) void naive_kernel(
    const float* __restrict__ x, const int* __restrict__ wq,
    const float* __restrict__ scale, const float* __restrict__ bias,
    float* __restrict__ out) {
    const int n = blockIdx.x * 256 + threadIdx.x;
    const int m = blockIdx.y;
    if (n >= Nd) return;
    const float* xr = x + (size_t)m * Kd;
    const int*   wr = wq + (size_t)n * Kd;
    float s = 0.f;
    for (int k = 0; k < Kd; ++k) s += xr[k] * (float)wr[k];
    out[(size_t)m * Nd + n] = s * scale[n] + bias[n];
}

// ---------- launch ----------

extern "C" void kernel_launch(void* const* d_in, const int* in_sizes, int n_in,
                              void* d_out, int out_size, void* d_ws, size_t ws_size,
                              hipStream_t stream) {
    const float* x     = (const float*)d_in[0];
    const int*   wq    = (const int*)d_in[1];
    const float* scale = (const float*)d_in[2];
    const float* bias  = (const float*)d_in[3];
    float* out = (float*)d_out;

    const size_t w_bytes = (size_t)Nd * Kd * sizeof(unsigned short);
    const size_t x_bytes = (size_t)Md * Kd * sizeof(unsigned short);
    if (ws_size >= w_bytes + x_bytes && d_ws != nullptr) {
        unsigned short* wb = (unsigned short*)d_ws;
        unsigned short* xb = wb + (size_t)Nd * Kd;
        convert_w_kernel<<<4096, 256, 0, stream>>>(wq, wb);
        convert_x_kernel<<<2048, 256, 0, stream>>>(x, xb);
        gemm8_kernel<<<256, 512, 0, stream>>>(xb, wb, scale, bias, out);
    } else {
        dim3 grid(Nd / 256, Md);
        naive_kernel<<<grid, 256, 0, stream>>>(x, wq, scale, bias, out);
    }
}

// Round 5
// 142.947 us; speedup vs baseline: 1.8876x; 1.8876x over previous
//
#include <hip/hip_runtime.h>

typedef __attribute__((ext_vector_type(4))) float f32x4;
typedef __attribute__((ext_vector_type(4))) int   i32x4;

static constexpr int Kd = 4096, Nd = 16384, Md = 1024;
static constexpr int BK = 128;          // K-bytes per tile (i8 elements)
static constexpr int NT = Kd / BK;      // 32 K-tiles

// ---------- helpers ----------

__device__ __forceinline__ void gload16(const char* g, char* l) {
    __builtin_amdgcn_global_load_lds(
        (const __attribute__((address_space(1))) void*)g,
        (__attribute__((address_space(3))) void*)l, 16, 0, 0);
}

__device__ __forceinline__ int pack4(int a, int b, int c, int d) {
    return (a & 255) | ((b & 255) << 8) | ((c & 255) << 16) | (d << 24);
}

// ---------- convert W: int32 [N][K] -> int8 (exact) ----------

__global__ __launch_bounds__(256) void convert_w_kernel(
    const int* __restrict__ wq, char* __restrict__ wb) {
    const int ngroups = (Nd / 16) * Kd;      // groups of 16 elems
    int g = blockIdx.x * 256 + threadIdx.x;
    const int stride = gridDim.x * 256;
    for (; g < ngroups; g += stride) {
        const int* src = wq + (size_t)g * 16;
        i32x4 a = *(const i32x4*)(src);
        i32x4 b = *(const i32x4*)(src + 4);
        i32x4 c = *(const i32x4*)(src + 8);
        i32x4 d = *(const i32x4*)(src + 12);
        i32x4 o;
        o[0] = pack4(a[0], a[1], a[2], a[3]);
        o[1] = pack4(b[0], b[1], b[2], b[3]);
        o[2] = pack4(c[0], c[1], c[2], c[3]);
        o[3] = pack4(d[0], d[1], d[2], d[3]);
        *(i32x4*)(wb + (size_t)g * 16) = o;
    }
}

// ---------- convert X: f32 [M][K] -> per-row absmax-scaled int8 ----------
// one block (256 threads) per row; each thread covers 16 consecutive floats

__global__ __launch_bounds__(256) void convert_x_kernel(
    const float* __restrict__ x, char* __restrict__ xb, float* __restrict__ xs) {
    const int row = blockIdx.x;
    const int t   = threadIdx.x;
    const float* xr = x + (size_t)row * Kd;

    f32x4 v[4];
    float amax = 0.f;
    #pragma unroll
    for (int i = 0; i < 4; ++i) {
        v[i] = *(const f32x4*)(xr + t * 16 + i * 4);
        #pragma unroll
        for (int j = 0; j < 4; ++j) amax = fmaxf(amax, fabsf(v[i][j]));
    }
    #pragma unroll
    for (int off = 32; off; off >>= 1)
        amax = fmaxf(amax, __shfl_xor(amax, off));
    __shared__ float wmax[4];
    if ((t & 63) == 0) wmax[t >> 6] = amax;
    __syncthreads();
    amax = fmaxf(fmaxf(wmax[0], wmax[1]), fmaxf(wmax[2], wmax[3]));
    amax = fmaxf(amax, 1e-20f);

    const float inv = 127.0f / amax;
    i32x4 o;
    #pragma unroll
    for (int i = 0; i < 4; ++i) {
        int q[4];
        #pragma unroll
        for (int j = 0; j < 4; ++j) {
            int qi = __float2int_rn(v[i][j] * inv);
            qi = qi > 127 ? 127 : (qi < -127 ? -127 : qi);
            q[j] = qi;
        }
        o[i] = pack4(q[0], q[1], q[2], q[3]);
    }
    *(i32x4*)(xb + (size_t)row * Kd + t * 16) = o;
    if (t == 0) xs[row] = amax * (1.0f / 127.0f);
}

// ---------- 256x256 i8 GEMM, round-3 schedule, BK=128 bytes ----------
// C[m,n] = s_w[n]*s_x[m] * sum_k xq[m,k]*wq[n,k] + bias[n]
// Byte-geometry identical to the bf16 round-3 kernel (rows = 128 B):
// same XOR swizzle, staging, fragment offsets; MFMA = i32_16x16x64_i8.
// 8 waves = 2M x 4N; per-wave 128x64 out; LDS 128 KiB, 2 slots.
// Per K-tile, 4 phases (C-quadrants), fragments register-cached:
//   P1: read A0(8xb128)+B0(4); P2: read B1(4); P3: read A1(8); P4: none.
// Stages: P1 A_hi(t+1), P2 B_hi(t+1) [other slot]; P3 A_lo(t+2),
// P4 B_lo(t+2) [same slot]. vmcnt(4) once per tile at P4.

#define BARRIER() asm volatile("s_barrier" ::: "memory")

#define LGKM0_FENCE() do {                                                     \
    asm volatile("s_waitcnt lgkmcnt(0)");                                      \
    __builtin_amdgcn_sched_barrier(0);                                         \
} while (0)

#define STAGE_A(slot, h, kt) do {                                              \
    char* lb_ = &LDS[slot][0][h][w * 8][0];                                    \
    gload16(Ab + (aRow0 + (h) * 64) * (size_t)Kd + (kt) * BK + gcol, lb_);     \
    gload16(Ab + (aRow0 + (h) * 64 + 128) * (size_t)Kd + (kt) * BK + gcol,     \
            lb_ + 64 * 128);                                                   \
} while (0)

#define STAGE_B(slot, j, kt) do {                                              \
    char* lb_ = &LDS[slot][1][j][w * 8][0];                                    \
    gload16(Bw + (bRow0 + (j) * 32) * (size_t)Kd + (kt) * BK + gcol, lb_);     \
    gload16(Bw + (bRow0 + (j) * 32 + 128) * (size_t)Kd + (kt) * BK + gcol,     \
            lb_ + 64 * 128);                                                   \
} while (0)

#define READ_A(dst, slot, h) do {                                              \
    const char* lA_ = &LDS[slot][0][h][0][0];                                  \
    _Pragma("unroll")                                                          \
    for (int mi = 0; mi < 4; ++mi)                                             \
        _Pragma("unroll")                                                      \
        for (int kk = 0; kk < 2; ++kk) {                                       \
            const int row_ = wm * 64 + mi * 16 + lr;                           \
            const int col_ = (l4 * 16 + kk * 64) ^ xorv;                       \
            dst[mi][kk] = *(const i32x4*)(lA_ + row_ * 128 + col_);            \
        }                                                                      \
} while (0)

#define READ_B(dst, slot, j) do {                                              \
    const char* lB_ = &LDS[slot][1][j][0][0];                                  \
    _Pragma("unroll")                                                          \
    for (int ni = 0; ni < 2; ++ni)                                             \
        _Pragma("unroll")                                                      \
        for (int kk = 0; kk < 2; ++kk) {                                       \
            const int row_ = wn * 32 + ni * 16 + lr;                           \
            const int col_ = (l4 * 16 + kk * 64) ^ xorv;                       \
            dst[ni][kk] = *(const i32x4*)(lB_ + row_ * 128 + col_);            \
        }                                                                      \
} while (0)

#define MFMA_QUAD(h, j, AF, BF) do {                                           \
    __builtin_amdgcn_s_setprio(1);                                             \
    _Pragma("unroll")                                                          \
    for (int mi = 0; mi < 4; ++mi)                                             \
        _Pragma("unroll")                                                      \
        for (int ni = 0; ni < 2; ++ni)                                         \
            _Pragma("unroll")                                                  \
            for (int kk = 0; kk < 2; ++kk)                                     \
                acc[(h) * 4 + mi][(j) * 2 + ni] =                              \
                    __builtin_amdgcn_mfma_i32_16x16x64_i8(                     \
                        AF[mi][kk], BF[ni][kk],                                \
                        acc[(h) * 4 + mi][(j) * 2 + ni], 0, 0, 0);             \
    __builtin_amdgcn_s_setprio(0);                                             \
} while (0)

#define VMCNT_TILE(t)                                                          \
    do {                                                                       \
        if ((t) + 2 < NT) asm volatile("s_waitcnt vmcnt(4)" ::: "memory");     \
        else              asm volatile("s_waitcnt vmcnt(0)" ::: "memory");     \
    } while (0)

#define TILE(slot, oslot, t) do {                                              \
    i32x4 afA[4][2], afB[4][2], bfA[2][2], bfB[2][2];                          \
    /* P1: quadrant (0,0) */                                                   \
    READ_A(afA, slot, 0);                                                      \
    READ_B(bfA, slot, 0);                                                      \
    if ((t) + 1 < NT) STAGE_A(oslot, 1, (t) + 1);                              \
    BARRIER(); LGKM0_FENCE();                                                  \
    MFMA_QUAD(0, 0, afA, bfA);                                                 \
    BARRIER();                                                                 \
    /* P2: quadrant (0,1) */                                                   \
    READ_B(bfB, slot, 1);                                                      \
    if ((t) + 1 < NT) STAGE_B(oslot, 1, (t) + 1);                              \
    BARRIER(); LGKM0_FENCE();                                                  \
    MFMA_QUAD(0, 1, afA, bfB);                                                 \
    BARRIER();                                                                 \
    /* P3: quadrant (1,0) */                                                   \
    READ_A(afB, slot, 1);                                                      \
    if ((t) + 2 < NT) STAGE_A(slot, 0, (t) + 2);                               \
    BARRIER(); LGKM0_FENCE();                                                  \
    MFMA_QUAD(1, 0, afB, bfA);                                                 \
    BARRIER();                                                                 \
    /* P4: quadrant (1,1) — no LDS reads, frags cached */                      \
    if ((t) + 2 < NT) STAGE_B(slot, 0, (t) + 2);                               \
    VMCNT_TILE(t);                                                             \
    BARRIER();                                                                 \
    MFMA_QUAD(1, 1, afB, bfB);                                                 \
    BARRIER();                                                                 \
} while (0)

__global__ __launch_bounds__(512, 2) void gemm8_kernel(
    const char* __restrict__ Ab,        // xq [M][K] i8
    const char* __restrict__ Bw,        // wq [N][K] i8
    const float* __restrict__ sw,       // per-n weight scale
    const float* __restrict__ xs,       // per-m activation scale
    const float* __restrict__ bias,
    float* __restrict__ C) {

    __shared__ __align__(16) char LDS[2][2][2][128][128];   // 128 KiB

    const int tid = threadIdx.x;
    const int l   = tid & 63;
    const int w   = tid >> 6;          // wave 0..7
    const int wm  = w >> 2;            // 0..1
    const int wn  = w & 3;             // 0..3
    const int lr  = l & 15;
    const int l4  = l >> 4;            // 0..3
    const int xorv = (lr & 7) << 4;

    // bijective XCD swizzle (256 wg, 32/XCD), m-fastest work order
    const int orig = blockIdx.x;
    const int work = (orig & 7) * 32 + (orig >> 3);
    const int gm0 = (work & 3) * 256;
    const int gn0 = (work >> 2) * 256;

    // staging source geometry (inverse of read-side XOR swizzle), 16B units
    const int g_log = (l & 7) ^ ((l >> 3) & 7);
    const int gcol  = g_log * 16;
    const size_t aRow0 = (size_t)(gm0 + w * 8 + (l >> 3));
    const size_t bRow0 = (size_t)(gn0 + (w >> 2) * 64 + (w & 3) * 8 + (l >> 3));

    i32x4 acc[8][4];
    #pragma unroll
    for (int i = 0; i < 8; ++i)
        #pragma unroll
        for (int j = 0; j < 4; ++j) {
            i32x4 z = {0, 0, 0, 0};
            acc[i][j] = z;
        }

    // prologue: tile0 complete + tile1 lo-regions
    STAGE_A(0, 0, 0); STAGE_B(0, 0, 0);
    STAGE_A(0, 1, 0); STAGE_B(0, 1, 0);
    STAGE_A(1, 0, 1); STAGE_B(1, 0, 1);
    asm volatile("s_waitcnt vmcnt(4)" ::: "memory");
    BARRIER();

    #pragma unroll 1
    for (int tt = 0; tt < NT / 2; ++tt) {
        TILE(0, 1, 2 * tt);
        TILE(1, 0, 2 * tt + 1);
    }

    // epilogue: C = sw[n]*xs[m]*acc + bias[n]
    // C/D layout (dtype-independent): col = lane&15 (n), row = (lane>>4)*4+reg
    #pragma unroll
    for (int bj = 0; bj < 4; ++bj) {
        const int gn = gn0 + wn * 64 + bj * 16 + lr;
        const float sc = sw[gn];
        const float bi = bias[gn];
        #pragma unroll
        for (int ai = 0; ai < 8; ++ai) {
            const int gm = gm0 + wm * 128 + ai * 16 + l4 * 4;
            #pragma unroll
            for (int r = 0; r < 4; ++r)
                C[(size_t)(gm + r) * Nd + gn] =
                    (float)acc[ai][bj][r] * (sc * xs[gm + r]) + bi;
        }
    }
}

// ---------- fallback (ws too small): slow but correct ----------

__global__ __launch_bounds__(256) void naive_kernel(
    const float* __restrict__ x, const int* __restrict__ wq,
    const float* __restrict__ scale, const float* __restrict__ bias,
    float* __restrict__ out) {
    const int n = blockIdx.x * 256 + threadIdx.x;
    const int m = blockIdx.y;
    if (n >= Nd) return;
    const float* xr = x + (size_t)m * Kd;
    const int*   wr = wq + (size_t)n * Kd;
    float s = 0.f;
    for (int k = 0; k < Kd; ++k) s += xr[k] * (float)wr[k];
    out[(size_t)m * Nd + n] = s * scale[n] + bias[n];
}

// ---------- launch ----------

extern "C" void kernel_launch(void* const* d_in, const int* in_sizes, int n_in,
                              void* d_out, int out_size, void* d_ws, size_t ws_size,
                              hipStream_t stream) {
    const float* x     = (const float*)d_in[0];
    const int*   wq    = (const int*)d_in[1];
    const float* scale = (const float*)d_in[2];
    const float* bias  = (const float*)d_in[3];
    float* out = (float*)d_out;

    const size_t w_bytes = (size_t)Nd * Kd;              // 64 MiB (i8)
    const size_t x_bytes = (size_t)Md * Kd;              //  4 MiB (i8)
    const size_t s_bytes = (size_t)Md * sizeof(float);   //  4 KiB
    if (ws_size >= w_bytes + x_bytes + s_bytes && d_ws != nullptr) {
        char*  wb = (char*)d_ws;
        char*  xb = wb + w_bytes;
        float* xs = (float*)(xb + x_bytes);
        convert_w_kernel<<<4096, 256, 0, stream>>>(wq, wb);
        convert_x_kernel<<<Md, 256, 0, stream>>>(x, xb, xs);
        gemm8_kernel<<<256, 512, 0, stream>>>(xb, wb, scale, xs, bias, out);
    } else {
        dim3 grid(Nd / 256, Md);
        naive_kernel<<<grid, 256, 0, stream>>>(x, wq, scale, bias, out);
    }
}